// Round 4
// baseline (1489.542 us; speedup 1.0000x reference)
//
#include <hip/hip_runtime.h>
#include <hip/hip_fp16.h>

#define TSTEPS 276
#define NBATCH 32768
#define KDIM   4416   // 276*16
#define NPAD   320    // Wfc rows padded to 2.5*128
#define NOUT   276

typedef _Float16 half8 __attribute__((ext_vector_type(8)));
typedef float    f32x4 __attribute__((ext_vector_type(4)));

__device__ __forceinline__ float fast_sigmoid(float x) {
    float e = __builtin_amdgcn_exp2f(-1.4426950408889634f * x);
    return __builtin_amdgcn_rcpf(1.0f + e);
}
__device__ __forceinline__ float fast_tanh(float x) {
    float e = __builtin_amdgcn_exp2f(2.885390081777927f * x);
    return 1.0f - 2.0f * __builtin_amdgcn_rcpf(1.0f + e);
}

// ---------------- Kernel 1: bidirectional LSTM (exact R2 version, 469 us) ----
// 8 lanes per (row, dir): lane k owns h_k,c_k and gate rows {k,8+k,16+k,24+k}.
// h broadcast within the 8-lane group via __shfl. Stores h as fp16 in flat
// layout [b_local][t][dir*8+k].
__global__ __launch_bounds__(256) void lstm_kernel(
    const float* __restrict__ x,
    const float* __restrict__ Wih_f, const float* __restrict__ Whh_f,
    const float* __restrict__ bih_f, const float* __restrict__ bhh_f,
    const float* __restrict__ Wih_b, const float* __restrict__ Whh_b,
    const float* __restrict__ bih_b, const float* __restrict__ bhh_b,
    int row0, _Float16* __restrict__ Hout)
{
    const int tid = threadIdx.x;
    const int k   = tid & 7;
    const int rd  = blockIdx.x * 32 + (tid >> 3);
    const int bl  = rd >> 1;
    const int dir = rd & 1;
    const int bg  = row0 + bl;

    const float* Wih = dir ? Wih_b : Wih_f;
    const float* Whh = dir ? Whh_b : Whh_f;
    const float* bih = dir ? bih_b : bih_f;
    const float* bhh = dir ? bhh_b : bhh_f;

    float Wk[4][8], Wi0[4], Wi1[4], bs[4];
    #pragma unroll
    for (int g = 0; g < 4; ++g) {
        int row = g * 8 + k;                       // PyTorch gate order i,f,g,o
        #pragma unroll
        for (int j = 0; j < 8; ++j) Wk[g][j] = Whh[row * 8 + j];
        Wi0[g] = Wih[row * 2 + 0];
        Wi1[g] = Wih[row * 2 + 1];
        bs[g]  = bih[row] + bhh[row];
    }

    const int laneBase = tid & 56;
    const float2* __restrict__ xrow = (const float2*)(x + (size_t)bg * (TSTEPS * 2));
    _Float16* __restrict__ hrow = Hout + (size_t)bl * KDIM + dir * 8 + k;

    float h = 0.0f, c = 0.0f;
    for (int s = 0; s < TSTEPS; ++s) {
        const int tau = dir ? (TSTEPS - 1 - s) : s;
        const float2 xv = xrow[tau];

        float hv[8];
        #pragma unroll
        for (int j = 0; j < 8; ++j) hv[j] = __shfl(h, laneBase + j, 64);

        float a[4];
        #pragma unroll
        for (int g = 0; g < 4; ++g) {
            float acc = fmaf(xv.x, Wi0[g], bs[g]);
            acc = fmaf(xv.y, Wi1[g], acc);
            #pragma unroll
            for (int j = 0; j < 8; ++j) acc = fmaf(Wk[g][j], hv[j], acc);
            a[g] = acc;
        }
        const float ig = fast_sigmoid(a[0]);
        const float fg = fast_sigmoid(a[1]);
        const float gg = fast_tanh(a[2]);
        const float og = fast_sigmoid(a[3]);
        c = fmaf(fg, c, ig * gg);
        h = og * fast_tanh(c);

        hrow[tau * 16] = (_Float16)h;
    }
}

// ---------------- Kernel 2: Wfc fp32 -> fp16, padded to NPAD rows ----------------
__global__ __launch_bounds__(256) void conv_kernel(const float* __restrict__ Wfc,
                                                   _Float16* __restrict__ W2)
{
    int i = blockIdx.x * 256 + threadIdx.x;
    if (i < NPAD * KDIM) {
        int n = i / KDIM;
        W2[i] = (n < NOUT) ? (_Float16)Wfc[i] : (_Float16)0.0f;
    }
}

// ---------------- Kernel 3: out[rows,276] = H[rows,4416] * W2^T + bfc ----------
// LDS-staged, full-N per block so A is read from HBM exactly once.
// Block tile 64(M) x 320(N), K-chunk 32. 4 waves: wave tile 32(M) x 160(N)
// = 2x10 16x16x32 MFMA tiles (acc 80 VGPR). Next chunk's global data is
// prefetched into VGPRs during the MFMA phase (consumed at next ds_write).
// LDS K-stride padded 32->36 halfs: bank conflicts <=2-way (free).
__global__ __launch_bounds__(256, 2) void gemm_kernel(
    const _Float16* __restrict__ H, const _Float16* __restrict__ W2,
    const float* __restrict__ bfc, float* __restrict__ out)
{
    __shared__ _Float16 As[64][36];    // 4.6 KB
    __shared__ _Float16 Bs[320][36];   // 23.0 KB

    const int tid  = threadIdx.x;
    const int lane = tid & 63;
    const int w    = tid >> 6;
    const int wm   = w >> 1;           // m-half (32 rows)
    const int wn   = w & 1;            // n-half (160 cols)
    const int m0   = blockIdx.x * 64;
    const int l15  = lane & 15;
    const int l4   = lane >> 4;

    // staging: A = 64 rows x 64B -> 1 seg/thread; B = 320 rows x 64B -> 5 segs
    const int srow = tid >> 2;         // 0..63
    const int sq   = (tid & 3) * 8;    // half offset within k-chunk
    const _Float16* Aglob = H  + (size_t)(m0 + srow) * KDIM + sq;
    const _Float16* Bglob = W2 + (size_t)srow * KDIM + sq;

    int4 apre, bpre[5];
    apre = *(const int4*)Aglob;
    #pragma unroll
    for (int i = 0; i < 5; ++i)
        bpre[i] = *(const int4*)(Bglob + (size_t)(i * 64) * KDIM);

    f32x4 acc[2][10] = {};

    for (int k0 = 0; k0 < KDIM; k0 += 32) {
        if (k0) __syncthreads();                       // LDS readers done
        *(int4*)&As[srow][sq] = apre;
        #pragma unroll
        for (int i = 0; i < 5; ++i)
            *(int4*)&Bs[srow + i * 64][sq] = bpre[i];
        __syncthreads();

        const int k1 = k0 + 32;                        // prefetch next chunk
        if (k1 < KDIM) {
            apre = *(const int4*)(Aglob + k1);
            #pragma unroll
            for (int i = 0; i < 5; ++i)
                bpre[i] = *(const int4*)(Bglob + (size_t)(i * 64) * KDIM + k1);
        }

        half8 af[2];
        #pragma unroll
        for (int mi = 0; mi < 2; ++mi)
            af[mi] = *(const half8*)&As[wm * 32 + mi * 16 + l15][l4 * 8];
        #pragma unroll
        for (int ni = 0; ni < 10; ++ni) {
            half8 bf = *(const half8*)&Bs[wn * 160 + ni * 16 + l15][l4 * 8];
            acc[0][ni] = __builtin_amdgcn_mfma_f32_16x16x32_f16(af[0], bf, acc[0][ni], 0, 0, 0);
            acc[1][ni] = __builtin_amdgcn_mfma_f32_16x16x32_f16(af[1], bf, acc[1][ni], 0, 0, 0);
        }
    }

    // C layout (16x16): col = lane&15, row = (lane>>4)*4 + reg
    #pragma unroll
    for (int mi = 0; mi < 2; ++mi) {
        const int mrow = m0 + wm * 32 + mi * 16 + l4 * 4;
        #pragma unroll
        for (int ni = 0; ni < 10; ++ni) {
            const int n = wn * 160 + ni * 16 + l15;
            if (n < NOUT) {
                const float bv = bfc[n];
                #pragma unroll
                for (int g = 0; g < 4; ++g)
                    out[(size_t)(mrow + g) * NOUT + n] = acc[mi][ni][g] + bv;
            }
        }
    }
}

extern "C" void kernel_launch(void* const* d_in, const int* in_sizes, int n_in,
                              void* d_out, int out_size, void* d_ws, size_t ws_size,
                              hipStream_t stream) {
    const float* x     = (const float*)d_in[0];
    const float* Wih_f = (const float*)d_in[1];
    const float* Whh_f = (const float*)d_in[2];
    const float* bih_f = (const float*)d_in[3];
    const float* bhh_f = (const float*)d_in[4];
    const float* Wih_b = (const float*)d_in[5];
    const float* Whh_b = (const float*)d_in[6];
    const float* bih_b = (const float*)d_in[7];
    const float* bhh_b = (const float*)d_in[8];
    const float* Wfc   = (const float*)d_in[9];
    const float* bfc   = (const float*)d_in[10];
    float* out = (float*)d_out;

    // Workspace layout: [W2: NPAD*KDIM fp16][H chunk: chunk*KDIM fp16]
    _Float16* W2 = (_Float16*)d_ws;
    size_t h_off = ((size_t)NPAD * KDIM * 2 + 255) & ~(size_t)255;
    size_t avail = (ws_size > h_off) ? (ws_size - h_off) : 0;
    long maxrows = (long)(avail / ((size_t)KDIM * 2));
    int chunk = (int)((maxrows / 128) * 128);
    if (chunk > NBATCH) chunk = NBATCH;
    if (chunk < 128)    chunk = 128;
    _Float16* Hc = (_Float16*)((char*)d_ws + h_off);

    conv_kernel<<<(NPAD * KDIM + 255) / 256, 256, 0, stream>>>(Wfc, W2);

    for (int r0 = 0; r0 < NBATCH; r0 += chunk) {
        int rows = NBATCH - r0; if (rows > chunk) rows = chunk;
        lstm_kernel<<<rows / 16, 256, 0, stream>>>(x, Wih_f, Whh_f, bih_f, bhh_f,
                                                   Wih_b, Whh_b, bih_b, bhh_b,
                                                   r0, Hc);
        gemm_kernel<<<rows / 64, 256, 0, stream>>>(Hc, W2, bfc,
                                                   out + (size_t)r0 * NOUT);
    }
}

// Round 5
// 974.178 us; speedup vs baseline: 1.5290x; 1.5290x over previous
//
#include <hip/hip_runtime.h>
#include <hip/hip_fp16.h>

#define TSTEPS 276
#define NBATCH 32768
#define KDIM   4416   // 276*16
#define NPAD   320    // Wfc rows padded to 5*64
#define NOUT   276

typedef _Float16 half8 __attribute__((ext_vector_type(8)));
typedef float    f32x4 __attribute__((ext_vector_type(4)));

__device__ __forceinline__ float fast_sigmoid(float x) {
    float e = __builtin_amdgcn_exp2f(-1.4426950408889634f * x);
    return __builtin_amdgcn_rcpf(1.0f + e);
}
__device__ __forceinline__ float fast_tanh(float x) {
    float e = __builtin_amdgcn_exp2f(2.885390081777927f * x);
    return 1.0f - 2.0f * __builtin_amdgcn_rcpf(1.0f + e);
}

// ---------------- Kernel 1: bidirectional LSTM ----------------
// R2 structure (469 us proven) + x software-prefetch one step ahead
// (breaks the per-step dependent global load on the serial chain).
// No vector-type packing (R3's regression suspect).
__global__ __launch_bounds__(256) void lstm_kernel(
    const float* __restrict__ x,
    const float* __restrict__ Wih_f, const float* __restrict__ Whh_f,
    const float* __restrict__ bih_f, const float* __restrict__ bhh_f,
    const float* __restrict__ Wih_b, const float* __restrict__ Whh_b,
    const float* __restrict__ bih_b, const float* __restrict__ bhh_b,
    int row0, _Float16* __restrict__ Hout)
{
    const int tid = threadIdx.x;
    const int k   = tid & 7;
    const int rd  = blockIdx.x * 32 + (tid >> 3);
    const int bl  = rd >> 1;
    const int dir = rd & 1;
    const int bg  = row0 + bl;

    const float* Wih = dir ? Wih_b : Wih_f;
    const float* Whh = dir ? Whh_b : Whh_f;
    const float* bih = dir ? bih_b : bih_f;
    const float* bhh = dir ? bhh_b : bhh_f;

    float Wk[4][8], Wi0[4], Wi1[4], bs[4];
    #pragma unroll
    for (int g = 0; g < 4; ++g) {
        int row = g * 8 + k;                       // PyTorch gate order i,f,g,o
        #pragma unroll
        for (int j = 0; j < 8; ++j) Wk[g][j] = Whh[row * 8 + j];
        Wi0[g] = Wih[row * 2 + 0];
        Wi1[g] = Wih[row * 2 + 1];
        bs[g]  = bih[row] + bhh[row];
    }

    const int laneBase = tid & 56;
    const float2* __restrict__ xrow = (const float2*)(x + (size_t)bg * (TSTEPS * 2));
    _Float16* __restrict__ hrow = Hout + (size_t)bl * KDIM + dir * 8 + k;

    float h = 0.0f, c = 0.0f;
    float2 xv = xrow[dir ? (TSTEPS - 1) : 0];
    for (int s = 0; s < TSTEPS; ++s) {
        const int tau = dir ? (TSTEPS - 1 - s) : s;
        const int sn  = (s + 1 < TSTEPS) ? (s + 1) : s;
        const int tau_n = dir ? (TSTEPS - 1 - sn) : sn;
        const float2 xv_n = xrow[tau_n];           // prefetch next step

        float hv[8];
        #pragma unroll
        for (int j = 0; j < 8; ++j) hv[j] = __shfl(h, laneBase + j, 64);

        float a[4];
        #pragma unroll
        for (int g = 0; g < 4; ++g) {
            float acc = fmaf(xv.x, Wi0[g], bs[g]);
            acc = fmaf(xv.y, Wi1[g], acc);
            #pragma unroll
            for (int j = 0; j < 8; ++j) acc = fmaf(Wk[g][j], hv[j], acc);
            a[g] = acc;
        }
        const float ig = fast_sigmoid(a[0]);
        const float fg = fast_sigmoid(a[1]);
        const float gg = fast_tanh(a[2]);
        const float og = fast_sigmoid(a[3]);
        c = fmaf(fg, c, ig * gg);
        h = og * fast_tanh(c);

        hrow[tau * 16] = (_Float16)h;
        xv = xv_n;
    }
}

// ---------------- Kernel 2: Wfc fp32 -> fp16, padded to NPAD rows ----------------
__global__ __launch_bounds__(256) void conv_kernel(const float* __restrict__ Wfc,
                                                   _Float16* __restrict__ W2)
{
    int i = blockIdx.x * 256 + threadIdx.x;
    if (i < NPAD * KDIM) {
        int n = i / KDIM;
        W2[i] = (n < NOUT) ? (_Float16)Wfc[i] : (_Float16)0.0f;
    }
}

// ---------------- Kernel 3: out[rows,276] = H[rows,4416] * W2^T + bfc ----------
// R2's proven kernel. ONLY change: grid transposed — blockIdx.x = n-tile (5),
// blockIdx.y = m-tile — so the 5 n-blocks sharing an A m-tile are
// dispatch-adjacent and the 4 re-reads of the 1.1 MB A tile hit L2/L3
// instead of streaming 289 MB x5 from HBM.
__global__ __launch_bounds__(256) void gemm_kernel(
    const _Float16* __restrict__ H, const _Float16* __restrict__ W2,
    const float* __restrict__ bfc, float* __restrict__ out)
{
    __shared__ _Float16 As[128][40];   // K-stride padded 32->40
    __shared__ _Float16 Bs[64][40];

    const int tid  = threadIdx.x;
    const int m0   = blockIdx.y * 128;
    const int n0   = blockIdx.x * 64;
    const int wid  = tid >> 6;
    const int lane = tid & 63;
    const int l15  = lane & 15;
    const int l4   = lane >> 4;

    f32x4 acc[2][4] = {};

    const int rA = tid >> 2;           // 0..63
    const int kp = (tid & 3) * 8;      // 0,8,16,24

    for (int k0 = 0; k0 < KDIM; k0 += 32) {
        const _Float16* Ap = H + (size_t)(m0 + rA) * KDIM + k0 + kp;
        int4 va0 = *(const int4*)Ap;
        int4 va1 = *(const int4*)(Ap + (size_t)64 * KDIM);
        int4 vb  = *(const int4*)(W2 + (size_t)(n0 + rA) * KDIM + k0 + kp);
        *(int4*)&As[rA][kp]      = va0;
        *(int4*)&As[rA + 64][kp] = va1;
        *(int4*)&Bs[rA][kp]      = vb;
        __syncthreads();

        half8 af[2], bf[4];
        #pragma unroll
        for (int mi = 0; mi < 2; ++mi)
            af[mi] = *(const half8*)&As[wid * 32 + mi * 16 + l15][l4 * 8];
        #pragma unroll
        for (int ni = 0; ni < 4; ++ni)
            bf[ni] = *(const half8*)&Bs[ni * 16 + l15][l4 * 8];
        #pragma unroll
        for (int mi = 0; mi < 2; ++mi)
            #pragma unroll
            for (int ni = 0; ni < 4; ++ni)
                acc[mi][ni] = __builtin_amdgcn_mfma_f32_16x16x32_f16(
                    af[mi], bf[ni], acc[mi][ni], 0, 0, 0);
        __syncthreads();
    }

    float bv[4];
    #pragma unroll
    for (int ni = 0; ni < 4; ++ni) {
        int n = n0 + ni * 16 + l15;
        bv[ni] = (n < NOUT) ? bfc[n] : 0.0f;
    }
    #pragma unroll
    for (int mi = 0; mi < 2; ++mi) {
        #pragma unroll
        for (int ni = 0; ni < 4; ++ni) {
            int n = n0 + ni * 16 + l15;
            if (n < NOUT) {
                int m = m0 + wid * 32 + mi * 16 + l4 * 4;
                #pragma unroll
                for (int r = 0; r < 4; ++r)
                    out[(size_t)(m + r) * NOUT + n] = acc[mi][ni][r] + bv[ni];
            }
        }
    }
}

extern "C" void kernel_launch(void* const* d_in, const int* in_sizes, int n_in,
                              void* d_out, int out_size, void* d_ws, size_t ws_size,
                              hipStream_t stream) {
    const float* x     = (const float*)d_in[0];
    const float* Wih_f = (const float*)d_in[1];
    const float* Whh_f = (const float*)d_in[2];
    const float* bih_f = (const float*)d_in[3];
    const float* bhh_f = (const float*)d_in[4];
    const float* Wih_b = (const float*)d_in[5];
    const float* Whh_b = (const float*)d_in[6];
    const float* bih_b = (const float*)d_in[7];
    const float* bhh_b = (const float*)d_in[8];
    const float* Wfc   = (const float*)d_in[9];
    const float* bfc   = (const float*)d_in[10];
    float* out = (float*)d_out;

    // Workspace layout: [W2: NPAD*KDIM fp16][H chunk: chunk*KDIM fp16]
    _Float16* W2 = (_Float16*)d_ws;
    size_t h_off = ((size_t)NPAD * KDIM * 2 + 255) & ~(size_t)255;
    size_t avail = (ws_size > h_off) ? (ws_size - h_off) : 0;
    long maxrows = (long)(avail / ((size_t)KDIM * 2));
    int chunk = (int)((maxrows / 128) * 128);
    if (chunk > NBATCH) chunk = NBATCH;
    if (chunk < 128)    chunk = 128;
    _Float16* Hc = (_Float16*)((char*)d_ws + h_off);

    conv_kernel<<<(NPAD * KDIM + 255) / 256, 256, 0, stream>>>(Wfc, W2);

    for (int r0 = 0; r0 < NBATCH; r0 += chunk) {
        int rows = NBATCH - r0; if (rows > chunk) rows = chunk;
        lstm_kernel<<<rows / 16, 256, 0, stream>>>(x, Wih_f, Whh_f, bih_f, bhh_f,
                                                   Wih_b, Whh_b, bih_b, bhh_b,
                                                   r0, Hc);
        gemm_kernel<<<dim3(5, rows / 128), 256, 0, stream>>>(Hc, W2, bfc,
                                                             out + (size_t)r0 * NOUT);
    }
}

// Round 6
// 834.335 us; speedup vs baseline: 1.7853x; 1.1676x over previous
//
#include <hip/hip_runtime.h>
#include <hip/hip_fp16.h>

#define TSTEPS 276
#define NBATCH 32768
#define KDIM   4416   // 276*16
#define NPAD   320    // Wfc rows padded to 2*160
#define NOUT   276
#define BM     128
#define BN     160

typedef _Float16 half8 __attribute__((ext_vector_type(8)));
typedef float    f32x4 __attribute__((ext_vector_type(4)));

__device__ __forceinline__ float fast_sigmoid(float x) {
    float e = __builtin_amdgcn_exp2f(-1.4426950408889634f * x);
    return __builtin_amdgcn_rcpf(1.0f + e);
}
__device__ __forceinline__ float fast_tanh(float x) {
    float e = __builtin_amdgcn_exp2f(2.885390081777927f * x);
    return 1.0f - 2.0f * __builtin_amdgcn_rcpf(1.0f + e);
}

__device__ __forceinline__ void async_copy16(const void* g, void* l) {
    __builtin_amdgcn_global_load_lds(
        (const __attribute__((address_space(1))) void*)g,
        (__attribute__((address_space(3))) void*)l, 16, 0, 0);
}

// ---------------- Kernel 1: bidirectional LSTM ----------------
// R5 structure with two targeted fixes:
// (a) __launch_bounds__(256,4): 128-VGPR budget so the 44 weight floats stay
//     resident (R5: VGPR_Count=36 -> weights reloaded every step, ~2.7x VALU).
// (b) bwd stores TIME-REVERSED: both dirs write hrow[s*16] at step s, so the
//     fwd and bwd halves of each 32B (b,t)-sector are written together
//     (R5: WRITE_SIZE 683MB for 289MB data). W2 gets the matching K-perm.
__global__ __launch_bounds__(256, 4) void lstm_kernel(
    const float* __restrict__ x,
    const float* __restrict__ Wih_f, const float* __restrict__ Whh_f,
    const float* __restrict__ bih_f, const float* __restrict__ bhh_f,
    const float* __restrict__ Wih_b, const float* __restrict__ Whh_b,
    const float* __restrict__ bih_b, const float* __restrict__ bhh_b,
    int row0, _Float16* __restrict__ Hout)
{
    const int tid = threadIdx.x;
    const int k   = tid & 7;
    const int rd  = blockIdx.x * 32 + (tid >> 3);
    const int bl  = rd >> 1;
    const int dir = rd & 1;
    const int bg  = row0 + bl;

    const float* Wih = dir ? Wih_b : Wih_f;
    const float* Whh = dir ? Whh_b : Whh_f;
    const float* bih = dir ? bih_b : bih_f;
    const float* bhh = dir ? bhh_b : bhh_f;

    float Wk[4][8], Wi0[4], Wi1[4], bs[4];
    #pragma unroll
    for (int g = 0; g < 4; ++g) {
        int row = g * 8 + k;                       // PyTorch gate order i,f,g,o
        #pragma unroll
        for (int j = 0; j < 8; ++j) Wk[g][j] = Whh[row * 8 + j];
        Wi0[g] = Wih[row * 2 + 0];
        Wi1[g] = Wih[row * 2 + 1];
        bs[g]  = bih[row] + bhh[row];
    }

    const int laneBase = tid & 56;
    const float2* __restrict__ xrow = (const float2*)(x + (size_t)bg * (TSTEPS * 2));
    _Float16* __restrict__ hrow = Hout + (size_t)bl * KDIM + dir * 8 + k;

    float h = 0.0f, c = 0.0f;
    float2 xv = xrow[dir ? (TSTEPS - 1) : 0];
    for (int s = 0; s < TSTEPS; ++s) {
        const int sn  = (s + 1 < TSTEPS) ? (s + 1) : s;
        const float2 xv_n = xrow[dir ? (TSTEPS - 1 - sn) : sn];   // prefetch

        float hv[8];
        #pragma unroll
        for (int j = 0; j < 8; ++j) hv[j] = __shfl(h, laneBase + j, 64);

        float a[4];
        #pragma unroll
        for (int g = 0; g < 4; ++g) {
            float acc = fmaf(xv.x, Wi0[g], bs[g]);
            acc = fmaf(xv.y, Wi1[g], acc);
            #pragma unroll
            for (int j = 0; j < 8; ++j) acc = fmaf(Wk[g][j], hv[j], acc);
            a[g] = acc;
        }
        const float ig = fast_sigmoid(a[0]);
        const float fg = fast_sigmoid(a[1]);
        const float gg = fast_tanh(a[2]);
        const float og = fast_sigmoid(a[3]);
        c = fmaf(fg, c, ig * gg);
        h = og * fast_tanh(c);

        hrow[s * 16] = (_Float16)h;                // time-of-step layout (bwd reversed)
        xv = xv_n;
    }
}

// ---------------- Kernel 2: Wfc fp32 -> fp16 with K-permutation -------------
// H k-layout: p = s*16 + d*8 + j holds fwd h[t=s][j] (d=0) or bwd h[t=275-s][j]
// (d=1). So W2[n][p] = Wfc[n][p] for d=0, Wfc[n][(275-s)*16 + 8 + j] for d=1.
__global__ __launch_bounds__(256) void conv_kernel(const float* __restrict__ Wfc,
                                                   _Float16* __restrict__ W2)
{
    int i = blockIdx.x * 256 + threadIdx.x;
    if (i < NPAD * KDIM) {
        int n = i / KDIM, p = i - n * KDIM;
        _Float16 v = (_Float16)0.0f;
        if (n < NOUT) {
            int s = p >> 4, r = p & 15;
            int src = (r < 8) ? p : ((TSTEPS - 1 - s) * 16 + r);
            v = (_Float16)Wfc[n * KDIM + src];
        }
        W2[i] = v;
    }
}

// ---------------- Kernel 3: out[rows,276] = H[rows,4416] * W2^T + bfc -------
// m97-style: block 128(M) x 160(N), K-chunk 32, async global->LDS staging via
// global_load_lds width-16 (no staging VGPRs -> no R4-style spills). LDS is
// flat row-major [row][64B] (required lane-order for global_load_lds). 4 waves,
// wave tile 64x80 = 4x5 16x16x32 tiles (acc 80 VGPR), 9 ds_read_b128/chunk.
__global__ __launch_bounds__(256) void gemm_kernel(
    const _Float16* __restrict__ H, const _Float16* __restrict__ W2,
    const float* __restrict__ bfc, float* __restrict__ out)
{
    __shared__ char smem[(BM + BN) * 64];          // A at 0 (128x64B), B at 8192 (160x64B)

    const int tid  = threadIdx.x;
    const int lane = tid & 63;
    const int w    = tid >> 6;
    const int wm   = w >> 1;                       // m-half: 64 rows
    const int wn   = w & 1;                        // n-half: 80 cols
    const int m0   = blockIdx.y * BM;
    const int n0   = blockIdx.x * BN;
    const int l15  = lane & 15;
    const int l4   = lane >> 4;

    f32x4 acc[4][5] = {};

    for (int k0 = 0; k0 < KDIM; k0 += 32) {
        if (k0) __syncthreads();                   // readers of prev chunk done
        #pragma unroll
        for (int j = w; j < 8; j += 4) {           // A: 8 KB, 2 slots/wave
            int f = j * 1024 + lane * 16;
            const char* g = (const char*)(H + (size_t)(m0 + (f >> 6)) * KDIM + k0) + (f & 63);
            async_copy16(g, smem + j * 1024);
        }
        #pragma unroll
        for (int j = w; j < 10; j += 4) {          // B: 10 KB, 2-3 slots/wave
            int f = j * 1024 + lane * 16;
            const char* g = (const char*)(W2 + (size_t)(n0 + (f >> 6)) * KDIM + k0) + (f & 63);
            async_copy16(g, smem + 8192 + j * 1024);
        }
        __syncthreads();                           // drains vmcnt -> LDS visible

        half8 af[4];
        #pragma unroll
        for (int mi = 0; mi < 4; ++mi)
            af[mi] = *(const half8*)(smem + (wm * 64 + mi * 16 + l15) * 64 + l4 * 16);
        #pragma unroll
        for (int ni = 0; ni < 5; ++ni) {
            half8 bf = *(const half8*)(smem + 8192 + (wn * 80 + ni * 16 + l15) * 64 + l4 * 16);
            #pragma unroll
            for (int mi = 0; mi < 4; ++mi)
                acc[mi][ni] = __builtin_amdgcn_mfma_f32_16x16x32_f16(af[mi], bf, acc[mi][ni], 0, 0, 0);
        }
    }

    // C layout (16x16): col = lane&15, row = (lane>>4)*4 + reg
    #pragma unroll
    for (int ni = 0; ni < 5; ++ni) {
        const int n = n0 + wn * 80 + ni * 16 + l15;
        if (n < NOUT) {
            const float bv = bfc[n];
            #pragma unroll
            for (int mi = 0; mi < 4; ++mi) {
                const int mrow = m0 + wm * 64 + mi * 16 + l4 * 4;
                #pragma unroll
                for (int g = 0; g < 4; ++g)
                    out[(size_t)(mrow + g) * NOUT + n] = acc[mi][ni][g] + bv;
            }
        }
    }
}

extern "C" void kernel_launch(void* const* d_in, const int* in_sizes, int n_in,
                              void* d_out, int out_size, void* d_ws, size_t ws_size,
                              hipStream_t stream) {
    const float* x     = (const float*)d_in[0];
    const float* Wih_f = (const float*)d_in[1];
    const float* Whh_f = (const float*)d_in[2];
    const float* bih_f = (const float*)d_in[3];
    const float* bhh_f = (const float*)d_in[4];
    const float* Wih_b = (const float*)d_in[5];
    const float* Whh_b = (const float*)d_in[6];
    const float* bih_b = (const float*)d_in[7];
    const float* bhh_b = (const float*)d_in[8];
    const float* Wfc   = (const float*)d_in[9];
    const float* bfc   = (const float*)d_in[10];
    float* out = (float*)d_out;

    // Workspace layout: [W2: NPAD*KDIM fp16][H chunk: chunk*KDIM fp16]
    _Float16* W2 = (_Float16*)d_ws;
    size_t h_off = ((size_t)NPAD * KDIM * 2 + 255) & ~(size_t)255;
    size_t avail = (ws_size > h_off) ? (ws_size - h_off) : 0;
    long maxrows = (long)(avail / ((size_t)KDIM * 2));
    int chunk = (int)((maxrows / 128) * 128);
    if (chunk > NBATCH) chunk = NBATCH;
    if (chunk < 128)    chunk = 128;
    _Float16* Hc = (_Float16*)((char*)d_ws + h_off);

    conv_kernel<<<(NPAD * KDIM + 255) / 256, 256, 0, stream>>>(Wfc, W2);

    for (int r0 = 0; r0 < NBATCH; r0 += chunk) {
        int rows = NBATCH - r0; if (rows > chunk) rows = chunk;
        lstm_kernel<<<rows / 16, 256, 0, stream>>>(x, Wih_f, Whh_f, bih_f, bhh_f,
                                                   Wih_b, Whh_b, bih_b, bhh_b,
                                                   r0, Hc);
        gemm_kernel<<<dim3(2, rows / 128), 256, 0, stream>>>(Hc, W2, bfc,
                                                             out + (size_t)r0 * NOUT);
    }
}

// Round 7
// 775.372 us; speedup vs baseline: 1.9211x; 1.0760x over previous
//
#include <hip/hip_runtime.h>
#include <hip/hip_fp16.h>

#define TSTEPS 276
#define NBATCH 32768
#define KDIM   4416   // 276*16
#define NPAD   320    // Wfc rows padded to 2*160
#define NOUT   276
#define GBM    64     // gemm block M
#define GBN    320    // gemm block N (full)

typedef _Float16 half8 __attribute__((ext_vector_type(8)));
typedef float    f32x4 __attribute__((ext_vector_type(4)));

__device__ __forceinline__ float fast_sigmoid(float x) {
    float e = __builtin_amdgcn_exp2f(-1.4426950408889634f * x);
    return __builtin_amdgcn_rcpf(1.0f + e);
}
__device__ __forceinline__ float fast_tanh(float x) {
    float e = __builtin_amdgcn_exp2f(2.885390081777927f * x);
    return 1.0f - 2.0f * __builtin_amdgcn_rcpf(1.0f + e);
}

__device__ __forceinline__ void async_copy16(const void* g, void* l) {
    __builtin_amdgcn_global_load_lds(
        (const __attribute__((address_space(1))) void*)g,
        (__attribute__((address_space(3))) void*)l, 16, 0, 0);
}

// broadcast h from lane (lane&0x18)|j within each 8-lane group (BitMode swizzle,
// immediate pattern: and=0x18, or=j, xor=0 -> offset=(j<<5)|0x18). Groups are
// 8-aligned so they never cross the 32-lane swizzle half.
#define HSWZ(dst, hb, j) dst = __int_as_float(__builtin_amdgcn_ds_swizzle(hb, ((j) << 5) | 0x18))

// ---------------- Kernel 1: bidirectional LSTM ----------------
// R6 + (a) weights pinned in ArchVGPRs via empty asm (R6: VGPR_Count=36 ->
// compiler rematerialized 44 weight floats every step, ~80 extra insts/step);
// (b) ds_swizzle immediate broadcasts instead of __shfl (no addr computation).
__global__ __launch_bounds__(256, 4) void lstm_kernel(
    const float* __restrict__ x,
    const float* __restrict__ Wih_f, const float* __restrict__ Whh_f,
    const float* __restrict__ bih_f, const float* __restrict__ bhh_f,
    const float* __restrict__ Wih_b, const float* __restrict__ Whh_b,
    const float* __restrict__ bih_b, const float* __restrict__ bhh_b,
    int row0, _Float16* __restrict__ Hout)
{
    const int tid = threadIdx.x;
    const int k   = tid & 7;
    const int rd  = blockIdx.x * 32 + (tid >> 3);
    const int bl  = rd >> 1;
    const int dir = rd & 1;
    const int bg  = row0 + bl;

    const float* Wih = dir ? Wih_b : Wih_f;
    const float* Whh = dir ? Whh_b : Whh_f;
    const float* bih = dir ? bih_b : bih_f;
    const float* bhh = dir ? bhh_b : bhh_f;

    float Wk[4][8], Wi0[4], Wi1[4], bs[4];
    #pragma unroll
    for (int g = 0; g < 4; ++g) {
        int row = g * 8 + k;                       // PyTorch gate order i,f,g,o
        #pragma unroll
        for (int j = 0; j < 8; ++j) Wk[g][j] = Whh[row * 8 + j];
        Wi0[g] = Wih[row * 2 + 0];
        Wi1[g] = Wih[row * 2 + 1];
        bs[g]  = bih[row] + bhh[row];
    }
    // pin every weight in an ArchVGPR: forbids rematerialization/reload
    #pragma unroll
    for (int g = 0; g < 4; ++g) {
        #pragma unroll
        for (int j = 0; j < 8; ++j) asm volatile("" : "+v"(Wk[g][j]));
        asm volatile("" : "+v"(Wi0[g]));
        asm volatile("" : "+v"(Wi1[g]));
        asm volatile("" : "+v"(bs[g]));
    }

    const float2* __restrict__ xrow = (const float2*)(x + (size_t)bg * (TSTEPS * 2));
    _Float16* __restrict__ hrow = Hout + (size_t)bl * KDIM + dir * 8 + k;

    float h = 0.0f, c = 0.0f;
    float2 xv = xrow[dir ? (TSTEPS - 1) : 0];
    for (int s = 0; s < TSTEPS; ++s) {
        const int sn = (s + 1 < TSTEPS) ? (s + 1) : s;
        const float2 xv_n = xrow[dir ? (TSTEPS - 1 - sn) : sn];   // prefetch

        const int hb = __float_as_int(h);
        float hv[8];
        HSWZ(hv[0], hb, 0); HSWZ(hv[1], hb, 1); HSWZ(hv[2], hb, 2); HSWZ(hv[3], hb, 3);
        HSWZ(hv[4], hb, 4); HSWZ(hv[5], hb, 5); HSWZ(hv[6], hb, 6); HSWZ(hv[7], hb, 7);

        float a[4];
        #pragma unroll
        for (int g = 0; g < 4; ++g) {
            float acc = fmaf(xv.x, Wi0[g], bs[g]);
            acc = fmaf(xv.y, Wi1[g], acc);
            #pragma unroll
            for (int j = 0; j < 8; ++j) acc = fmaf(Wk[g][j], hv[j], acc);
            a[g] = acc;
        }
        const float ig = fast_sigmoid(a[0]);
        const float fg = fast_sigmoid(a[1]);
        const float gg = fast_tanh(a[2]);
        const float og = fast_sigmoid(a[3]);
        c = fmaf(fg, c, ig * gg);
        h = og * fast_tanh(c);

        hrow[s * 16] = (_Float16)h;                // time-of-step layout (bwd reversed)
        xv = xv_n;
    }
}

// ---------------- Kernel 2: Wfc fp32 -> fp16 with K-permutation -------------
// H k-layout: p = s*16 + d*8 + j holds fwd h[t=s][j] (d=0) or bwd h[t=275-s][j]
// (d=1). So W2[n][p] = Wfc[n][p] for d=0, Wfc[n][(275-s)*16 + 8 + j] for d=1.
__global__ __launch_bounds__(256) void conv_kernel(const float* __restrict__ Wfc,
                                                   _Float16* __restrict__ W2)
{
    int i = blockIdx.x * 256 + threadIdx.x;
    if (i < NPAD * KDIM) {
        int n = i / KDIM, p = i - n * KDIM;
        _Float16 v = (_Float16)0.0f;
        if (n < NOUT) {
            int s = p >> 4, r = p & 15;
            int src = (r < 8) ? p : ((TSTEPS - 1 - s) * 16 + r);
            v = (_Float16)Wfc[n * KDIM + src];
        }
        W2[i] = v;
    }
}

// ---------------- Kernel 3: out[rows,276] = H[rows,4416] * W2^T + bfc -------
// Double-buffered async staging: block 64(M) x 320(N=full, so A is read from
// HBM exactly once; B 2.8MB is L2-resident), K-chunk 32. Chunk k+1's
// global_load_lds are issued BEFORE computing chunk k; the wait happens at the
// next __syncthreads -> HBM latency overlaps compute (R6 version was fully
// serialized: load-drain-compute). No staging VGPRs -> no scratch spills.
// 4 waves, wave tile 32(M) x 160(N) = 2x10 16x16x32 tiles (80 acc VGPRs).
__global__ __launch_bounds__(256, 4) void gemm_kernel(
    const _Float16* __restrict__ H, const _Float16* __restrict__ W2,
    const float* __restrict__ bfc, float* __restrict__ out)
{
    __shared__ char smem[2][(GBM + GBN) * 64];     // per buf: A 4KB @0, B 20KB @4096

    const int tid  = threadIdx.x;
    const int lane = tid & 63;
    const int w    = tid >> 6;
    const int wm   = w >> 1;                       // 32-row half
    const int wn   = w & 1;                        // 160-col half
    const int m0   = blockIdx.x * GBM;
    const int l15  = lane & 15;
    const int l4   = lane >> 4;

    f32x4 acc[2][10] = {};

    // stage one 32-k chunk (24 KB = 24 slots of 1KB; 6 slots per wave)
    auto stage = [&](int k0, char* buf) {
        #pragma unroll
        for (int i = 0; i < 6; ++i) {
            const int j = w + 4 * i;               // 0..23, wave-uniform
            const int f = (j << 10) + lane * 16;
            const char* g;
            if (j < 4)                              // A region (4 KB)
                g = (const char*)(H + (size_t)(m0 + (f >> 6)) * KDIM + k0) + (f & 63);
            else {                                  // B region (20 KB)
                const int fb = f - 4096;
                g = (const char*)(W2 + (size_t)(fb >> 6) * KDIM + k0) + (fb & 63);
            }
            async_copy16(g, buf + (j << 10));
        }
    };

    stage(0, smem[0]);
    int cur = 0;
    for (int k0 = 0; k0 < KDIM; k0 += 32) {
        __syncthreads();                           // buf[cur] loads drained; prev compute done
        if (k0 + 32 < KDIM) stage(k0 + 32, smem[cur ^ 1]);

        const char* A  = smem[cur];
        const char* Bb = smem[cur] + 4096;
        half8 af[2];
        #pragma unroll
        for (int mi = 0; mi < 2; ++mi)
            af[mi] = *(const half8*)(A + (wm * 32 + mi * 16 + l15) * 64 + l4 * 16);
        #pragma unroll
        for (int ni = 0; ni < 10; ++ni) {
            half8 bf = *(const half8*)(Bb + (wn * 160 + ni * 16 + l15) * 64 + l4 * 16);
            #pragma unroll
            for (int mi = 0; mi < 2; ++mi)
                acc[mi][ni] = __builtin_amdgcn_mfma_f32_16x16x32_f16(af[mi], bf, acc[mi][ni], 0, 0, 0);
        }
        cur ^= 1;
    }

    // C layout (16x16): col = lane&15, row = (lane>>4)*4 + reg
    #pragma unroll
    for (int ni = 0; ni < 10; ++ni) {
        const int n = wn * 160 + ni * 16 + l15;
        if (n < NOUT) {
            const float bv = bfc[n];
            #pragma unroll
            for (int mi = 0; mi < 2; ++mi) {
                const int mbase = m0 + wm * 32 + mi * 16 + l4 * 4;
                #pragma unroll
                for (int g = 0; g < 4; ++g)
                    out[(size_t)(mbase + g) * NOUT + n] = acc[mi][ni][g] + bv;
            }
        }
    }
}

extern "C" void kernel_launch(void* const* d_in, const int* in_sizes, int n_in,
                              void* d_out, int out_size, void* d_ws, size_t ws_size,
                              hipStream_t stream) {
    const float* x     = (const float*)d_in[0];
    const float* Wih_f = (const float*)d_in[1];
    const float* Whh_f = (const float*)d_in[2];
    const float* bih_f = (const float*)d_in[3];
    const float* bhh_f = (const float*)d_in[4];
    const float* Wih_b = (const float*)d_in[5];
    const float* Whh_b = (const float*)d_in[6];
    const float* bih_b = (const float*)d_in[7];
    const float* bhh_b = (const float*)d_in[8];
    const float* Wfc   = (const float*)d_in[9];
    const float* bfc   = (const float*)d_in[10];
    float* out = (float*)d_out;

    // Workspace layout: [W2: NPAD*KDIM fp16][H chunk: chunk*KDIM fp16]
    _Float16* W2 = (_Float16*)d_ws;
    size_t h_off = ((size_t)NPAD * KDIM * 2 + 255) & ~(size_t)255;
    size_t avail = (ws_size > h_off) ? (ws_size - h_off) : 0;
    long maxrows = (long)(avail / ((size_t)KDIM * 2));
    int chunk = (int)((maxrows / 128) * 128);
    if (chunk > NBATCH) chunk = NBATCH;
    if (chunk < 128)    chunk = 128;
    _Float16* Hc = (_Float16*)((char*)d_ws + h_off);

    conv_kernel<<<(NPAD * KDIM + 255) / 256, 256, 0, stream>>>(Wfc, W2);

    for (int r0 = 0; r0 < NBATCH; r0 += chunk) {
        int rows = NBATCH - r0; if (rows > chunk) rows = chunk;
        lstm_kernel<<<rows / 16, 256, 0, stream>>>(x, Wih_f, Whh_f, bih_f, bhh_f,
                                                   Wih_b, Whh_b, bih_b, bhh_b,
                                                   r0, Hc);
        gemm_kernel<<<rows / 64, 256, 0, stream>>>(Hc, W2, bfc,
                                                   out + (size_t)r0 * NOUT);
    }
}